// Round 1
// baseline (1625.744 us; speedup 1.0000x reference)
//
#include <hip/hip_runtime.h>

// EmbeddingBag(mode='sum', include_last_offset=True) over F*B bags, then
// pooled.reshape(F,B,D).transpose(1,0,2) -> out[B,F,D].
//
// Strategy: one 64-lane wave per bag. Lane l accumulates dims [2l, 2l+1]
// as float2 -> each pool entry is one coalesced 512B global_load_dwordx2
// across the wave. Bag indices are prefetched lane-parallel (<=64 at a
// time) and broadcast with __shfl so gathers are independent; 4x manual
// unroll keeps multiple 512B loads in flight per wave.

#define F_FEATS 26
#define BATCH   4096
#define DIM     128
#define NUM_BAGS (F_FEATS * BATCH)

__global__ __launch_bounds__(256) void embag_sum_kernel(
    const int*   __restrict__ values,
    const int*   __restrict__ offsets,
    const float* __restrict__ table,
    float*       __restrict__ out)
{
    const int wave = blockIdx.x * (blockDim.x >> 6) + (threadIdx.x >> 6);
    if (wave >= NUM_BAGS) return;
    const int lane = threadIdx.x & 63;

    const int start = offsets[wave];
    const int end   = offsets[wave + 1];
    const int count = end - start;

    const float2* __restrict__ tab2 = (const float2*)table;
    float2 acc = make_float2(0.0f, 0.0f);

    for (int base = 0; base < count; base += 64) {
        const int chunk = min(64, count - base);
        int my_idx = 0;
        if (lane < chunk) my_idx = values[start + base + lane];

        int j = 0;
        for (; j + 4 <= chunk; j += 4) {
            const int i0 = __shfl(my_idx, j);
            const int i1 = __shfl(my_idx, j + 1);
            const int i2 = __shfl(my_idx, j + 2);
            const int i3 = __shfl(my_idx, j + 3);
            const float2 v0 = tab2[(size_t)i0 * (DIM / 2) + lane];
            const float2 v1 = tab2[(size_t)i1 * (DIM / 2) + lane];
            const float2 v2 = tab2[(size_t)i2 * (DIM / 2) + lane];
            const float2 v3 = tab2[(size_t)i3 * (DIM / 2) + lane];
            acc.x += v0.x + v1.x + v2.x + v3.x;
            acc.y += v0.y + v1.y + v2.y + v3.y;
        }
        for (; j < chunk; ++j) {
            const int i0 = __shfl(my_idx, j);
            const float2 v0 = tab2[(size_t)i0 * (DIM / 2) + lane];
            acc.x += v0.x;
            acc.y += v0.y;
        }
    }

    // bag = f * BATCH + b  ->  out[b][f][:]
    const int f = wave / BATCH;
    const int b = wave - f * BATCH;
    float2* __restrict__ out2 = (float2*)out;
    out2[((size_t)b * F_FEATS + f) * (DIM / 2) + lane] = acc;
}

extern "C" void kernel_launch(void* const* d_in, const int* in_sizes, int n_in,
                              void* d_out, int out_size, void* d_ws, size_t ws_size,
                              hipStream_t stream) {
    const int*   values  = (const int*)d_in[0];
    const int*   offsets = (const int*)d_in[1];
    const float* table   = (const float*)d_in[2];
    float*       out     = (float*)d_out;

    const int waves_per_block = 256 / 64;
    const int blocks = (NUM_BAGS + waves_per_block - 1) / waves_per_block;
    embag_sum_kernel<<<blocks, 256, 0, stream>>>(values, offsets, table, out);
}